// Round 7
// baseline (192.259 us; speedup 1.0000x reference)
//
#include <hip/hip_runtime.h>
#include <hip/hip_bf16.h>
#include <stdint.h>

typedef __attribute__((ext_vector_type(8))) __bf16 bf16x8;
typedef __attribute__((ext_vector_type(4))) float floatx4;

#define EPS 1e-5f

__device__ __forceinline__ unsigned short f2bf(float f) {
    union { float f; unsigned int u; } x; x.f = f;
    unsigned int r = x.u + 0x7fffu + ((x.u >> 16) & 1u);
    return (unsigned short)(r >> 16);
}
__device__ __forceinline__ float bf2f_lo(unsigned int u) {
    union { unsigned int u; float f; } x; x.u = u << 16; return x.f;
}
__device__ __forceinline__ float bf2f_hi(unsigned int u) {
    union { unsigned int u; float f; } x; x.u = u & 0xffff0000u; return x.f;
}

struct Params {
    const float* x_in;
    const int*   knn;
    const float* w1s[3];
    const float* w2s[3];
    const float* vws[2];
    unsigned short* W1P[3];
    unsigned short* W2P[3];
    unsigned short* VTP[2];
    const float* b1s[3];
    const float* b2s[3];
    const float* gs[3];
    const float* bes[3];
    const float* ms[3];
    const float* vvs[3];
    const float* vbb[2];
    const float* vgg[2];
    const float* vbt[2];
    const float* vmm[2];
    const float* vva[2];
    float* xf;
};

// ---------------- pack weights fragment-major (bf16), coalesced reads ------
// W1P: dst = hf*32768 + w*4096 + mt*2048 + ks*512 + q*128 + ln*8 + j
//      holds W1[k=32ks+8q+j][h=256hf+32w+16mt+ln]   (src [128][512])
// W2P: dst = hf*32768 + wg*8192 + nt*4096 + ks*512 + q*128 + ln*8 + j
//      holds W2[h=256hf+32ks+8q+j][c=32wg+16nt+ln]  (src [512][128])
// VTP: dst = wg*4096 + nt*2048 + ks*512 + q*128 + ln*8 + j
//      holds Wv[k=32ks+8q+j][c=32wg+16nt+ln]        (src [128][128])
__global__ __launch_bounds__(256) void pack_weights(Params P) {
    const int gtid = blockIdx.x * 256 + threadIdx.x;
    const int GT   = gridDim.x * 256;
#pragma unroll
    for (int t = 0; t < 3; ++t) {
        const float* s1 = P.w1s[t];
        unsigned short* d1 = P.W1P[t];
        for (int idx = gtid; idx < 65536; idx += GT) {
            int h = idx & 511, k = idx >> 9;
            int hf = h >> 8, w = (h >> 5) & 7, mt = (h >> 4) & 1, ln = h & 15;
            int ks = (k >> 5) & 3, q = (k >> 3) & 3, j = k & 7;
            d1[hf * 32768 + w * 4096 + mt * 2048 + ks * 512 + q * 128 + ln * 8 + j]
                = f2bf(s1[idx]);
        }
        const float* s2 = P.w2s[t];
        unsigned short* d2 = P.W2P[t];
        for (int idx = gtid; idx < 65536; idx += GT) {
            int c = idx & 127, h = idx >> 7;
            int hf = h >> 8, ks = (h >> 5) & 7, q = (h >> 3) & 3, j = h & 7;
            int wg = c >> 5, nt = (c >> 4) & 1, ln = c & 15;
            d2[hf * 32768 + wg * 8192 + nt * 4096 + ks * 512 + q * 128 + ln * 8 + j]
                = f2bf(s2[idx]);
        }
    }
#pragma unroll
    for (int t = 0; t < 2; ++t) {
        const float* sv = P.vws[t];
        unsigned short* dv = P.VTP[t];
        for (int idx = gtid; idx < 16384; idx += GT) {
            int c = idx & 127, k = idx >> 7;
            int ks = (k >> 5) & 3, q = (k >> 3) & 3, j = k & 7;
            int wg = c >> 5, nt = (c >> 4) & 1, ln = c & 15;
            dv[wg * 4096 + nt * 2048 + ks * 512 + q * 128 + ln * 8 + j] = f2bf(sv[idx]);
        }
    }
}

// ---------------- fused stage (512 thr = 8 waves, 64 points/block) ---------
// xt: 64 rows x 16 chunks (8 bf16), padded stride 17 chunks  (17408 B)
// ht: 64 pts  x 32 chunks (256 hid), padded stride 33 chunks (33792 B)
// Phases: [LOADX] x_in->xt | [TE] edge gather/max/BN/residual -> xt (bf16)
//         FFN (2 x 256-hid slices), epi2: xf = xt + BN(ffn) | [TV] VFR->VbOut
template <int LOADX, int TE, int TF, int TV>
__global__ __launch_bounds__(512, 4)
void stage(Params P, const float* __restrict__ xold_g,
           const unsigned short* __restrict__ VbIn,
           unsigned short* __restrict__ VbOut)
{
    __shared__ __align__(16) unsigned short xt[64 * 136];
    __shared__ __align__(16) unsigned short ht[64 * 264];
    const int tid  = threadIdx.x;
    const int lane = tid & 63;
    const int w    = tid >> 6;
    const int q    = lane >> 4;
    const int ln   = lane & 15;
    const int wg   = w & 3;          // ch group (32 ch)
    const int wh   = w >> 2;         // point half (32 pts)
    const int phys = blockIdx.x;
    const int bid  = (phys & 7) * 64 + (phys >> 3);   // XCD-local batches
    const int p0   = bid << 6;
    const floatx4 zero = {0.f, 0.f, 0.f, 0.f};

    if constexpr (LOADX) {
        const int r = tid >> 3, c = tid & 7;
        const float4* src = (const float4*)(xold_g + (size_t)(p0 + r) * 128 + c * 16);
#pragma unroll
        for (int i = 0; i < 2; ++i) {
            float4 a = src[2 * i], b = src[2 * i + 1];
            uint4 pk;
            pk.x = (unsigned int)f2bf(a.x) | ((unsigned int)f2bf(a.y) << 16);
            pk.y = (unsigned int)f2bf(a.z) | ((unsigned int)f2bf(a.w) << 16);
            pk.z = (unsigned int)f2bf(b.x) | ((unsigned int)f2bf(b.y) << 16);
            pk.w = (unsigned int)f2bf(b.z) | ((unsigned int)f2bf(b.w) << 16);
            *(uint4*)&xt[(r * 17 + c * 2 + i) * 8] = pk;
        }
    }

    if constexpr (TE >= 0) {
        const int ch0 = ln * 8;      // 8 channels per lane (16 B)
        float sc[8], of[8];
#pragma unroll
        for (int j2 = 0; j2 < 8; ++j2) {
            float g  = P.vgg[TE][ch0 + j2];
            float bt = P.vbt[TE][ch0 + j2];
            float mu = P.vmm[TE][ch0 + j2];
            float va = P.vva[TE][ch0 + j2];
            sc[j2] = g * rsqrtf(va + EPS);
            of[j2] = bt - mu * sc[j2];
        }
#pragma unroll
        for (int it = 0; it < 2; ++it) {
            const int pl = it * 32 + w * 4 + q;       // 4 points per wave
            const int p  = p0 + pl;
            const int b  = p >> 12;
            uint4 sv = *(const uint4*)(VbIn + (size_t)p * 128 + ch0);
            const int* kp = P.knn + (size_t)p * 16;
            int4 ka = *(const int4*)(kp);
            int4 kb = *(const int4*)(kp + 4);
            int4 kc = *(const int4*)(kp + 8);
            int4 kd = *(const int4*)(kp + 12);
            const unsigned short* vbase = VbIn + (((size_t)b << 12) << 7) + ch0;
            float m[8];
#pragma unroll
            for (int j2 = 0; j2 < 8; ++j2) m[j2] = -3.4e38f;
#define GATH(IDX) { uint4 u4 = *(const uint4*)(vbase + ((size_t)(IDX) << 7));      \
            m[0] = fmaxf(m[0], bf2f_lo(u4.x)); m[1] = fmaxf(m[1], bf2f_hi(u4.x)); \
            m[2] = fmaxf(m[2], bf2f_lo(u4.y)); m[3] = fmaxf(m[3], bf2f_hi(u4.y)); \
            m[4] = fmaxf(m[4], bf2f_lo(u4.z)); m[5] = fmaxf(m[5], bf2f_hi(u4.z)); \
            m[6] = fmaxf(m[6], bf2f_lo(u4.w)); m[7] = fmaxf(m[7], bf2f_hi(u4.w)); }
            GATH(ka.x) GATH(ka.y) GATH(ka.z) GATH(ka.w)
            GATH(kb.x) GATH(kb.y) GATH(kb.z) GATH(kb.w)
            GATH(kc.x) GATH(kc.y) GATH(kc.z) GATH(kc.w)
            GATH(kd.x) GATH(kd.y) GATH(kd.z) GATH(kd.w)
#undef GATH
            const float* xrow = xold_g + (size_t)p * 128 + ch0;
            float4 x0 = *(const float4*)xrow;
            float4 x1 = *(const float4*)(xrow + 4);
            float s_[8];
            s_[0] = bf2f_lo(sv.x); s_[1] = bf2f_hi(sv.x);
            s_[2] = bf2f_lo(sv.y); s_[3] = bf2f_hi(sv.y);
            s_[4] = bf2f_lo(sv.z); s_[5] = bf2f_hi(sv.z);
            s_[6] = bf2f_lo(sv.w); s_[7] = bf2f_hi(sv.w);
            float xo[8] = {x0.x, x0.y, x0.z, x0.w, x1.x, x1.y, x1.z, x1.w};
            unsigned int pw[8];
#pragma unroll
            for (int j2 = 0; j2 < 8; ++j2) {
                float xn = xo[j2] + (m[j2] - s_[j2]) * sc[j2] + of[j2];
                pw[j2] = (unsigned int)f2bf(xn);
            }
            uint4 pk;
            pk.x = pw[0] | (pw[1] << 16);
            pk.y = pw[2] | (pw[3] << 16);
            pk.z = pw[4] | (pw[5] << 16);
            pk.w = pw[6] | (pw[7] << 16);
            *(uint4*)&xt[(pl * 17 + ln) * 8] = pk;
        }
    }
    __syncthreads();

    // ---------------- FFN: 2 x 256-hid slices ----------------
    floatx4 acc2[2][2];
#pragma unroll
    for (int i = 0; i < 2; ++i)
#pragma unroll
        for (int j = 0; j < 2; ++j) acc2[i][j] = zero;

    const unsigned short* W1 = P.W1P[TF];
    const unsigned short* W2 = P.W2P[TF];
    const float* b1 = P.b1s[TF];

#pragma unroll
    for (int hf = 0; hf < 2; ++hf) {
        // GEMM1: wave owns 32 hid (2 m-frags); LDS reads shared across both
        floatx4 acc1[2][4];
#pragma unroll
        for (int i = 0; i < 2; ++i)
#pragma unroll
            for (int j = 0; j < 4; ++j) acc1[i][j] = zero;
        const unsigned short* a1 = W1 + hf * 32768 + w * 4096 + q * 128 + ln * 8;
#pragma unroll
        for (int ks = 0; ks < 4; ++ks) {
            bf16x8 bfr[4];
#pragma unroll
            for (int nt = 0; nt < 4; ++nt)
                bfr[nt] = *(const bf16x8*)&xt[((16 * nt + ln) * 17 + 4 * ks + q) * 8];
#pragma unroll
            for (int mt = 0; mt < 2; ++mt) {
                bf16x8 af = *(const bf16x8*)(a1 + mt * 2048 + ks * 512);
#pragma unroll
                for (int nt = 0; nt < 4; ++nt)
                    acc1[mt][nt] = __builtin_amdgcn_mfma_f32_16x16x32_bf16(
                        af, bfr[nt], acc1[mt][nt], 0, 0, 0);
            }
        }
        if (hf > 0) __syncthreads();   // prior GEMM2 readers of ht done
        // epilogue1: +b1, relu, pack 4 hid -> ht
#pragma unroll
        for (int mt = 0; mt < 2; ++mt) {
            const int hloc = 32 * w + 16 * mt + 4 * q;
            const int gh   = 256 * hf + hloc;
            const float bv0 = b1[gh], bv1 = b1[gh + 1];
            const float bv2 = b1[gh + 2], bv3 = b1[gh + 3];
            const int c16  = hloc >> 3;
            const int half = q & 1;
#pragma unroll
            for (int nt = 0; nt < 4; ++nt) {
                const int pt = 16 * nt + ln;
                float v0 = acc1[mt][nt][0] + bv0; v0 = v0 > 0.f ? v0 : 0.f;
                float v1 = acc1[mt][nt][1] + bv1; v1 = v1 > 0.f ? v1 : 0.f;
                float v2 = acc1[mt][nt][2] + bv2; v2 = v2 > 0.f ? v2 : 0.f;
                float v3 = acc1[mt][nt][3] + bv3; v3 = v3 > 0.f ? v3 : 0.f;
                uint2 pk;
                pk.x = (unsigned int)f2bf(v0) | ((unsigned int)f2bf(v1) << 16);
                pk.y = (unsigned int)f2bf(v2) | ((unsigned int)f2bf(v3) << 16);
                *(uint2*)&ht[(pt * 33 + c16) * 8 + half * 4] = pk;
            }
        }
        __syncthreads();
        // GEMM2: wave owns 32 ch x 32 pts
        const unsigned short* b2b = W2 + hf * 32768 + wg * 8192 + q * 128 + ln * 8;
#pragma unroll
        for (int ks = 0; ks < 8; ++ks) {
            bf16x8 bw[2];
#pragma unroll
            for (int nt = 0; nt < 2; ++nt)
                bw[nt] = *(const bf16x8*)(b2b + nt * 4096 + ks * 512);
#pragma unroll
            for (int mt = 0; mt < 2; ++mt) {
                const int pt = 32 * wh + 16 * mt + ln;
                bf16x8 ah = *(const bf16x8*)&ht[(pt * 33 + 4 * ks + q) * 8];
#pragma unroll
                for (int nt = 0; nt < 2; ++nt)
                    acc2[mt][nt] = __builtin_amdgcn_mfma_f32_16x16x32_bf16(
                        ah, bw[nt], acc2[mt][nt], 0, 0, 0);
            }
        }
    }

    // epilogue2: xf = bf16base(xt) + BN(acc2 + b2); update xt for VFR
    {
        const float* b2   = P.b2s[TF];
        const float* gam  = P.gs[TF];
        const float* bet  = P.bes[TF];
        const float* mean = P.ms[TF];
        const float* var  = P.vvs[TF];
#pragma unroll
        for (int nt = 0; nt < 2; ++nt) {
            const int c = 32 * wg + 16 * nt + ln;
            const float scv = gam[c] * rsqrtf(var[c] + EPS);
            const float off = (b2[c] - mean[c]) * scv + bet[c];
#pragma unroll
            for (int mt = 0; mt < 2; ++mt) {
#pragma unroll
                for (int r = 0; r < 4; ++r) {
                    const int pt = 32 * wh + 16 * mt + 4 * q + r;
                    const int xa = (pt * 17 + (c >> 3)) * 8 + (c & 7);
                    float base = bf2f_lo((unsigned int)xt[xa]);
                    float xn = base + acc2[mt][nt][r] * scv + off;
                    P.xf[(size_t)(p0 + pt) * 128 + c] = xn;
                    if constexpr (TV >= 0) xt[xa] = f2bf(xn);
                }
            }
        }
    }

    // ---------------- VFR linear ----------------
    if constexpr (TV >= 0) {
        __syncthreads();
        const unsigned short* VT = P.VTP[TV];
        floatx4 acc[2][2];
#pragma unroll
        for (int i = 0; i < 2; ++i)
#pragma unroll
            for (int j = 0; j < 2; ++j) acc[i][j] = zero;
        const unsigned short* bb2 = VT + wg * 4096 + q * 128 + ln * 8;
#pragma unroll
        for (int ks = 0; ks < 4; ++ks) {
            bf16x8 bw[2];
#pragma unroll
            for (int nt = 0; nt < 2; ++nt)
                bw[nt] = *(const bf16x8*)(bb2 + nt * 2048 + ks * 512);
#pragma unroll
            for (int mt = 0; mt < 2; ++mt) {
                const int pt = 32 * wh + 16 * mt + ln;
                bf16x8 ax = *(const bf16x8*)&xt[(pt * 17 + 4 * ks + q) * 8];
#pragma unroll
                for (int nt = 0; nt < 2; ++nt)
                    acc[mt][nt] = __builtin_amdgcn_mfma_f32_16x16x32_bf16(
                        ax, bw[nt], acc[mt][nt], 0, 0, 0);
            }
        }
        const float* vb = P.vbb[TV];
#pragma unroll
        for (int nt = 0; nt < 2; ++nt) {
            const int c = 32 * wg + 16 * nt + ln;
            const float bia = vb[c];
#pragma unroll
            for (int mt = 0; mt < 2; ++mt)
#pragma unroll
                for (int r = 0; r < 4; ++r) {
                    const int pt = 32 * wh + 16 * mt + 4 * q + r;
                    VbOut[(size_t)(p0 + pt) * 128 + c] = f2bf(acc[mt][nt][r] + bia);
                }
        }
    }
}

// ---------------- launch ----------------
extern "C" void kernel_launch(void* const* d_in, const int* in_sizes, int n_in,
                              void* d_out, int out_size, void* d_ws, size_t ws_size,
                              hipStream_t stream)
{
    Params p;
    p.x_in = (const float*)d_in[0];
    p.knn  = (const int*)d_in[1];
    const float* w1  = (const float*)d_in[2];
    const float* b1  = (const float*)d_in[3];
    const float* w2  = (const float*)d_in[4];
    const float* b2  = (const float*)d_in[5];
    const float* g0  = (const float*)d_in[6];
    const float* be0 = (const float*)d_in[7];
    const float* m0p = (const float*)d_in[8];
    const float* v0p = (const float*)d_in[9];
    const float* vw  = (const float*)d_in[10];
    const float* vbp = (const float*)d_in[11];
    const float* vgp = (const float*)d_in[12];
    const float* vbe = (const float*)d_in[13];
    const float* vmp = (const float*)d_in[14];
    const float* vvp = (const float*)d_in[15];
    const float* fw1 = (const float*)d_in[16];
    const float* fb1 = (const float*)d_in[17];
    const float* fw2 = (const float*)d_in[18];
    const float* fb2 = (const float*)d_in[19];
    const float* fg  = (const float*)d_in[20];
    const float* fbe = (const float*)d_in[21];
    const float* fm  = (const float*)d_in[22];
    const float* fv  = (const float*)d_in[23];

    p.w1s[0] = w1;  p.w1s[1] = fw1; p.w1s[2] = fw1 + 65536;
    p.w2s[0] = w2;  p.w2s[1] = fw2; p.w2s[2] = fw2 + 65536;
    p.vws[0] = vw;  p.vws[1] = vw + 16384;
    p.b1s[0] = b1;  p.b1s[1] = fb1; p.b1s[2] = fb1 + 512;
    p.b2s[0] = b2;  p.b2s[1] = fb2; p.b2s[2] = fb2 + 128;
    p.gs[0]  = g0;  p.gs[1]  = fg;  p.gs[2]  = fg + 128;
    p.bes[0] = be0; p.bes[1] = fbe; p.bes[2] = fbe + 128;
    p.ms[0]  = m0p; p.ms[1]  = fm;  p.ms[2]  = fm + 128;
    p.vvs[0] = v0p; p.vvs[1] = fv;  p.vvs[2] = fv + 128;
    p.vbb[0] = vbp; p.vbb[1] = vbp + 128;
    p.vgg[0] = vgp; p.vgg[1] = vgp + 128;
    p.vbt[0] = vbe; p.vbt[1] = vbe + 128;
    p.vmm[0] = vmp; p.vmm[1] = vmp + 128;
    p.vva[0] = vvp; p.vva[1] = vvp + 128;

    char* ws = (char*)d_ws;
    unsigned short* Vb0 = (unsigned short*)ws;                          // 8 MiB
    unsigned short* Vb1 = (unsigned short*)(ws + (size_t)(8 << 20));    // 8 MiB
    unsigned short* u   = (unsigned short*)(ws + (size_t)(16 << 20));   // packed weights
    for (int i = 0; i < 3; ++i) p.W1P[i] = u + i * 65536;
    for (int i = 0; i < 3; ++i) p.W2P[i] = u + 196608 + i * 65536;
    for (int i = 0; i < 2; ++i) p.VTP[i] = u + 393216 + i * 16384;
    p.xf = (float*)d_out;

    pack_weights<<<dim3(512), 256, 0, stream>>>(p);
    stage<1, -1, 0, 0><<<dim3(512), 512, 0, stream>>>(p, p.x_in, nullptr, Vb0);
    stage<0,  0, 1, 1><<<dim3(512), 512, 0, stream>>>(p, p.xf, Vb0, Vb1);
    stage<0,  1, 2, -1><<<dim3(512), 512, 0, stream>>>(p, p.xf, Vb1, nullptr);
}